// Round 1
// baseline (265.337 us; speedup 1.0000x reference)
//
#include <hip/hip_runtime.h>
#include <hip/hip_bf16.h>

// 2D-MDLSTM (4 directions) + FC head for MI355X.
//
// Design:
//  - kernel 1 (mdlstm): 256 WGs = 4 dirs x 64 batch-pairs, 256 thr (4 waves).
//    Each WG scans its own 28x28 grid along 55 anti-diagonals; cells on a
//    diagonal x 2 batch are packed into the M dim of mfma_f32_16x16x32_f16.
//    U (one direction) pre-packed into per-lane f16 B-fragments held in
//    REGISTERS (20 x f16x8 = 80 VGPR) -> no per-step weight traffic.
//    h/c frontier in LDS, row-REVERSED so [h_left|h_up] is one contiguous
//    128-f16 slice (direct ds_read_b128 A-fragments). Double-buffered per
//    diagonal -> exactly one __syncthreads per diagonal (55 total).
//  - kernel 2 (fc): per-batch-row FC(256->512) relu FC(512->10) softmax.

#define GRIDN 28
#define BATCH 128
#define HID   64
#define NDIR  4
#define FC_HD 512
#define OUT_N 10
#define BT    2            // batch elements per WG
#define NSLOT 29           // 28 frontier rows + permanent-zero row (r = -1)

typedef _Float16 f16;
typedef _Float16 f16x8 __attribute__((ext_vector_type(8)));
typedef float    f32x4 __attribute__((ext_vector_type(4)));

__device__ __forceinline__ float sigf(float x)      { return 1.0f / (1.0f + __expf(-x)); }
__device__ __forceinline__ float tanh_fast(float x) { return 2.0f / (1.0f + __expf(-2.0f * x)) - 1.0f; }

__global__ __launch_bounds__(256, 1)
void mdlstm_kernel(const float* __restrict__ x,    // [B][28][28]
                   const float* __restrict__ Wx,   // [4][320]
                   const float* __restrict__ U,    // [4][128][320]
                   const float* __restrict__ bias, // [4][320]
                   float* __restrict__ Hout)       // [4][B][64]
{
    const int d    = blockIdx.x & 3;
    const int tile = blockIdx.x >> 2;     // 0..63 batch-pair
    const int tid  = threadIdx.x;
    const int lane = tid & 63;
    const int w    = tid >> 6;            // wave 0..3 -> h-subtile w*16..
    const int l16  = lane & 15;
    const int q    = lane >> 4;           // quad 0..3

    // frontier: Fh[buf][b][slot*64+h], slot = 27 - row (reversed!), slot 28 == zeros (r=-1)
    __shared__ __align__(16) f16 Fh[2][BT][NSLOT * HID];
    __shared__ float             Fc[2][BT][NSLOT * HID];
    __shared__ float             xs[GRIDN][GRIDN][BT]; // direction-flipped x

    for (int i = tid; i < 2 * BT * NSLOT * HID; i += 256) {
        ((f16*)Fh)[i]   = (f16)0.0f;
        ((float*)Fc)[i] = 0.0f;
    }
    for (int i = tid; i < GRIDN * GRIDN * BT; i += 256) {
        int bl = i & 1, rc = i >> 1, c = rc % GRIDN, r = rc / GRIDN;
        int rr = (d & 2) ? (GRIDN - 1 - r) : r;
        int cc = (d & 1) ? (GRIDN - 1 - c) : c;
        int bg = tile * BT + bl;
        xs[r][c][bl] = x[(bg * GRIDN + rr) * GRIDN + cc];
    }

    // Per-lane weights. B-frag for 16x16x32 f16: lane holds B[k=ks*32+q*8+j][n=l16 in tile].
    // Tile for (gate g, wave w) covers cols g*64 + w*16 + l16.
    const int n_base = w * 16 + l16;
    f16x8 bfrag[5][4];
    float wxv[5], bbv[5];
#pragma unroll
    for (int g = 0; g < 5; ++g) {
        int n = g * 64 + n_base;
        wxv[g] = Wx[d * 320 + n];
        bbv[g] = bias[d * 320 + n];
#pragma unroll
        for (int ks = 0; ks < 4; ++ks) {
            f16x8 v;
            int kb = ks * 32 + q * 8;
#pragma unroll
            for (int j = 0; j < 8; ++j)
                v[j] = (f16)U[(d * 128 + kb + j) * 320 + n];
            bfrag[g][ks] = v;
        }
    }
    __syncthreads();

    for (int t = 0; t < 2 * GRIDN - 1; ++t) {
        const int rlo   = (t > GRIDN - 1) ? (t - (GRIDN - 1)) : 0;
        const int rhi   = (t < GRIDN - 1) ? t : (GRIDN - 1);
        const int k     = rhi - rlo + 1;
        const int nrows = k * BT;
        const int nM    = (nrows + 15) >> 4;
        const int br = t & 1, bw = br ^ 1;

        for (int mt = 0; mt < nM; ++mt) {
            // ---- A fragment: A row m = l16, task row = mt*16+l16 -> (cell, batch)
            int mA = mt * 16 + l16;
            int jA = mA >> 1; if (jA > k - 1) jA = k - 1;   // clamp padding rows
            int bA = mA & 1;
            int rA = rlo + jA;
            f16x8 af[4];
#pragma unroll
            for (int ks = 0; ks < 4; ++ks)
                af[ks] = *(const f16x8*)&Fh[br][bA][(27 - rA) * HID + ks * 32 + q * 8];

            // ---- acc init with x*Wx + b ; C/D rows = q*4 + i
            float xv[4]; int rowD[4], bD[4], rD[4];
#pragma unroll
            for (int i = 0; i < 4; ++i) {
                int rd = mt * 16 + q * 4 + i;
                int jj = rd >> 1; if (jj > k - 1) jj = k - 1;
                bD[i] = rd & 1;
                rD[i] = rlo + jj;
                rowD[i] = rd;
                xv[i] = xs[rD[i]][t - rD[i]][bD[i]];
            }
            f32x4 acc[5];
#pragma unroll
            for (int g = 0; g < 5; ++g) {
                f32x4 a;
#pragma unroll
                for (int i = 0; i < 4; ++i) a[i] = xv[i] * wxv[g] + bbv[g];
                acc[g] = a;
            }
#pragma unroll
            for (int ks = 0; ks < 4; ++ks) {
#pragma unroll
                for (int g = 0; g < 5; ++g)
                    acc[g] = __builtin_amdgcn_mfma_f32_16x16x32_f16(af[ks], bfrag[g][ks], acc[g], 0, 0, 0);
            }
            // ---- gates + state update (lane-local: all 5 gates of (row,h) in this lane)
#pragma unroll
            for (int i = 0; i < 4; ++i) {
                if (rowD[i] < nrows) {
                    int sl = (27 - rD[i]) * HID + n_base;   // this row's slot
                    int su = (28 - rD[i]) * HID + n_base;   // row-1 slot (contiguous next)
                    float cl = Fc[br][bD[i]][sl];
                    float cu = Fc[br][bD[i]][su];
                    float ig = sigf(acc[0][i]);
                    float f1 = sigf(acc[1][i]);
                    float f2 = sigf(acc[2][i]);
                    float og = sigf(acc[3][i]);
                    float gg = tanh_fast(acc[4][i]);
                    float cn = ig * gg + f1 * cl + f2 * cu;
                    float hn = og * tanh_fast(cn);
                    Fc[bw][bD[i]][sl] = cn;
                    Fh[bw][bD[i]][sl] = (f16)hn;
                }
            }
        }
        __syncthreads();   // writes of diag t visible before diag t+1 reads
    }

    // final h(27,27) sits in buf 1 (t=54 writes buf (54&1)^1 = 1), slot 0
    if (tid < BT * HID) {
        int bl = tid >> 6, h = tid & 63;
        int bg = tile * BT + bl;
        Hout[(d * BATCH + bg) * HID + h] = (float)Fh[1][bl][h];
    }
}

__global__ __launch_bounds__(256, 1)
void fc_kernel(const float* __restrict__ Hin,  // [4][B][64]
               const float* __restrict__ W1, const float* __restrict__ b1,
               const float* __restrict__ W2, const float* __restrict__ b2,
               float* __restrict__ out)        // [B][10]
{
    const int b = blockIdx.x;
    const int tid = threadIdx.x;
    __shared__ float hrow[NDIR * HID];
    __shared__ float z1[FC_HD];
    __shared__ float w2s[FC_HD * OUT_N];
    __shared__ float z2[OUT_N];

    hrow[tid] = Hin[(tid >> 6) * BATCH * HID + b * HID + (tid & 63)];
    for (int i = tid; i < FC_HD * OUT_N; i += 256) w2s[i] = W2[i];
    __syncthreads();

    for (int j = tid; j < FC_HD; j += 256) {
        float s = b1[j];
#pragma unroll 8
        for (int f = 0; f < NDIR * HID; ++f) s += hrow[f] * W1[f * FC_HD + j];
        z1[j] = fmaxf(s, 0.0f);
    }
    __syncthreads();

    if (tid < OUT_N) {
        float s = b2[tid];
        for (int i = 0; i < FC_HD; ++i) s += z1[i] * w2s[i * OUT_N + tid];
        z2[tid] = s;
    }
    __syncthreads();

    if (tid == 0) {
        float m = z2[0];
        for (int j = 1; j < OUT_N; ++j) m = fmaxf(m, z2[j]);
        float s = 0.0f, e[OUT_N];
        for (int j = 0; j < OUT_N; ++j) { e[j] = __expf(z2[j] - m); s += e[j]; }
        float inv = 1.0f / s;
        for (int j = 0; j < OUT_N; ++j) out[b * OUT_N + j] = e[j] * inv;
    }
}

extern "C" void kernel_launch(void* const* d_in, const int* in_sizes, int n_in,
                              void* d_out, int out_size, void* d_ws, size_t ws_size,
                              hipStream_t stream) {
    const float* x  = (const float*)d_in[0];
    const float* Wx = (const float*)d_in[1];
    const float* U  = (const float*)d_in[2];
    const float* bs = (const float*)d_in[3];
    const float* W1 = (const float*)d_in[4];
    const float* b1 = (const float*)d_in[5];
    const float* W2 = (const float*)d_in[6];
    const float* b2 = (const float*)d_in[7];
    float* out = (float*)d_out;
    float* Hws = (float*)d_ws;   // [4][128][64] fp32 = 128 KiB

    mdlstm_kernel<<<NDIR * (BATCH / BT), 256, 0, stream>>>(x, Wx, U, bs, Hws);
    fc_kernel<<<BATCH, 256, 0, stream>>>(Hws, W1, b1, W2, b2, out);
}

// Round 3
// 182.233 us; speedup vs baseline: 1.4560x; 1.4560x over previous
//
#include <hip/hip_runtime.h>
#include <hip/hip_bf16.h>

// 2D-MDLSTM (4 directions) + FC head for MI355X — round 2 (resubmit; R2 bench
// was lost to a GPU-broker acquisition timeout, kernel never ran).
//
// Changes vs round 1 (186 us mdlstm, VALU-bound, 1 wave/SIMD, 16-way LDS
// conflicts on A-frag reads):
//  - 512-thread WGs (8 waves): wave = (wm, wh); the <=4 M-tiles of a
//    diagonal are split across wm=0/1 -> 2 waves/SIMD latency hiding,
//    serial tile-steps 124 -> 78.
//  - x*Wx + bias folded into the MFMA as a 5th K-step: each Fh slot has an
//    x-region [64..96) = {x, 1, 0...}; B-frag ks=4 = {Wx[n], b[n], 0...}.
//    Removes per-tile xs gathers and acc-init FMAs (acc starts at 0).
//    x for diagonal t+1 staged by the mostly-idle last wave during diag t.
//  - v_rcp_f32 (__builtin_amdgcn_rcpf) instead of exact fdiv in
//    sigmoid/tanh: ~12 -> 4 instrs each (no -ffast-math in harness).
//  - Bank-conflict padding: Fh slot stride 104 f16 (even 4-bank-group
//    distribution for ds_read_b128), Fc stride 68 floats (2-way max = free).

#define GRIDN 28
#define BATCH 128
#define HID   64
#define NDIR  4
#define FC_HD 512
#define OUT_N 10
#define BT    2
#define NSLOT 29          // 28 frontier rows + permanent-zero row (r = -1)
#define S_H   104         // f16/slot: [0,64) h | [64]=x [65]=1 [66,96)=0 | 8 pad
#define S_C   68          // float/slot: 64 c + 4 pad

typedef _Float16 f16;
typedef _Float16 f16x8 __attribute__((ext_vector_type(8)));
typedef float    f32x4 __attribute__((ext_vector_type(4)));

__device__ __forceinline__ float sigf(float x) {
    return __builtin_amdgcn_rcpf(1.0f + __expf(-x));
}
__device__ __forceinline__ float tanh_fast(float x) {
    return 1.0f - 2.0f * __builtin_amdgcn_rcpf(1.0f + __expf(2.0f * x));
}

__global__ __launch_bounds__(512)
void mdlstm_kernel(const float* __restrict__ x,    // [B][28][28]
                   const float* __restrict__ Wx,   // [4][320]
                   const float* __restrict__ U,    // [4][128][320]
                   const float* __restrict__ bias, // [4][320]
                   float* __restrict__ Hout)       // [4][B][64]
{
    const int d    = blockIdx.x & 3;
    const int tile = blockIdx.x >> 2;     // 0..63 batch-pair
    const int tid  = threadIdx.x;
    const int lane = tid & 63;
    const int wave = tid >> 6;            // 0..7
    const int wm   = wave >> 2;           // tile parity 0/1
    const int wh   = wave & 3;            // h-subtile (n = wh*16 + l16)
    const int l16  = lane & 15;
    const int q    = lane >> 4;
    const int nb   = wh * 16 + l16;       // this lane's h index 0..63

    __shared__ __align__(16) f16 Fh[2][BT][NSLOT * S_H];
    __shared__ float             Fc[2][BT][NSLOT * S_C];
    __shared__ float             xs[GRIDN][GRIDN][BT];

    for (int i = tid; i < 2 * BT * NSLOT * S_H; i += 512) ((f16*)Fh)[i] = (f16)0.0f;
    for (int i = tid; i < 2 * BT * NSLOT * S_C; i += 512) ((float*)Fc)[i] = 0.0f;
    for (int i = tid; i < GRIDN * GRIDN * BT; i += 512) {
        int bl = i & 1, rc = i >> 1, c = rc % GRIDN, r = rc / GRIDN;
        int rr = (d & 2) ? (GRIDN - 1 - r) : r;
        int cc = (d & 1) ? (GRIDN - 1 - c) : c;
        xs[r][c][bl] = x[((tile * BT + bl) * GRIDN + rr) * GRIDN + cc];
    }

    // ---- B-fragments in registers: 5 gates x 5 ks = 25 x f16x8 (100 VGPR)
    // ks 0..3: U[k = ks*32 + q*8 + j][n];  ks 4: {Wx[n], bias[n], 0,...} @ q==0
    f16x8 bf[5][5];
#pragma unroll
    for (int g = 0; g < 5; ++g) {
        int n = g * 64 + nb;
#pragma unroll
        for (int ks = 0; ks < 4; ++ks) {
            f16x8 v;
            int kb = ks * 32 + q * 8;
#pragma unroll
            for (int j = 0; j < 8; ++j)
                v[j] = (f16)U[(d * 128 + kb + j) * 320 + n];
            bf[g][ks] = v;
        }
        f16x8 v5 = {(f16)0, (f16)0, (f16)0, (f16)0, (f16)0, (f16)0, (f16)0, (f16)0};
        if (q == 0) {
            v5[0] = (f16)Wx[d * 320 + n];
            v5[1] = (f16)bias[d * 320 + n];
        }
        bf[g][4] = v5;
    }
    __syncthreads();   // zero-init complete

    // ones in the x-region ([65]=1) of every slot, both buffers; seed x(0,0)
    if (tid < 2 * BT * NSLOT) {
        int buf = tid / (BT * NSLOT), rem = tid % (BT * NSLOT);
        int b = rem / NSLOT, sl = rem % NSLOT;
        Fh[buf][b][sl * S_H + 65] = (f16)1.0f;
    }
    if (tid < BT) Fh[0][tid][27 * S_H + 64] = (f16)xs[0][0][tid];
    __syncthreads();

    for (int t = 0; t < 2 * GRIDN - 1; ++t) {
        const int rlo = (t > GRIDN - 1) ? (t - (GRIDN - 1)) : 0;
        const int rhi = (t < GRIDN - 1) ? t : (GRIDN - 1);
        const int k   = rhi - rlo + 1;
        const int nM  = (2 * k + 15) >> 4;
        const int br  = t & 1, bw = br ^ 1;

        // stage x for diagonal t+1 into the write buffer (wave 7, often idle)
        if (t < 2 * GRIDN - 2 && tid >= 456) {
            int idx = tid - 456, b = idx & 1, j = idx >> 1;
            int rlo2 = (t + 1 > GRIDN - 1) ? (t + 1 - (GRIDN - 1)) : 0;
            int rhi2 = (t + 1 < GRIDN - 1) ? (t + 1) : (GRIDN - 1);
            if (j <= rhi2 - rlo2) {
                int r = rlo2 + j;
                Fh[bw][b][(27 - r) * S_H + 64] = (f16)xs[r][t + 1 - r][b];
            }
        }

        for (int mt = wm; mt < nM; mt += 2) {
            // ---- A fragments: task row mA -> (batch bA, grid row rA)
            int mA = mt * 16 + l16;
            int jA = mA >> 1; if (jA > k - 1) jA = k - 1;
            int bA = mA & 1;
            int slA = 27 - (rlo + jA);
            const f16* ab = &Fh[br][bA][slA * S_H];
            f16x8 a0 = *(const f16x8*)(ab + q * 8);              // h_left k 0..63
            f16x8 a1 = *(const f16x8*)(ab + 32 + q * 8);
            f16x8 a2 = *(const f16x8*)(ab + S_H + q * 8);        // h_up   k 64..127
            f16x8 a3 = *(const f16x8*)(ab + S_H + 32 + q * 8);
            f16x8 a4 = *(const f16x8*)(ab + 64 + q * 8);         // {x,1,0..} k 128..159

            f32x4 acc[5];
#pragma unroll
            for (int g = 0; g < 5; ++g) acc[g] = (f32x4){0.f, 0.f, 0.f, 0.f};
#pragma unroll
            for (int g = 0; g < 5; ++g) acc[g] = __builtin_amdgcn_mfma_f32_16x16x32_f16(a0, bf[g][0], acc[g], 0, 0, 0);
#pragma unroll
            for (int g = 0; g < 5; ++g) acc[g] = __builtin_amdgcn_mfma_f32_16x16x32_f16(a1, bf[g][1], acc[g], 0, 0, 0);
#pragma unroll
            for (int g = 0; g < 5; ++g) acc[g] = __builtin_amdgcn_mfma_f32_16x16x32_f16(a2, bf[g][2], acc[g], 0, 0, 0);
#pragma unroll
            for (int g = 0; g < 5; ++g) acc[g] = __builtin_amdgcn_mfma_f32_16x16x32_f16(a3, bf[g][3], acc[g], 0, 0, 0);
#pragma unroll
            for (int g = 0; g < 5; ++g) acc[g] = __builtin_amdgcn_mfma_f32_16x16x32_f16(a4, bf[g][4], acc[g], 0, 0, 0);

            // ---- gates + state.  D row rd = mt*16 + q*4 + i:
            //   i=0: (b0, j0)  i=1: (b1, j0)  i=2: (b0, j0+1)  i=3: (b1, j0+1)
            int j0  = mt * 8 + q * 2;
            int jj0 = (j0     > k - 1) ? k - 1 : j0;
            int jj1 = (j0 + 1 > k - 1) ? k - 1 : j0 + 1;
            bool g0 = j0 < k, g1 = j0 + 1 < k;
            int sl0 = 27 - (rlo + jj0);
            int sl1 = 27 - (rlo + jj1);
#pragma unroll
            for (int i = 0; i < 4; ++i) {
                int  b  = i & 1;
                int  sl = (i < 2) ? sl0 : sl1;
                bool gd = (i < 2) ? g0 : g1;
                float cl = Fc[br][b][sl * S_C + nb];
                float cu = Fc[br][b][(sl + 1) * S_C + nb];
                float ig = sigf(acc[0][i]);
                float f1 = sigf(acc[1][i]);
                float f2 = sigf(acc[2][i]);
                float og = sigf(acc[3][i]);
                float gg = tanh_fast(acc[4][i]);
                float cn = ig * gg + f1 * cl + f2 * cu;
                float hn = og * tanh_fast(cn);
                if (gd) {
                    Fc[bw][b][sl * S_C + nb] = cn;
                    Fh[bw][b][sl * S_H + nb] = (f16)hn;
                }
            }
        }
        __syncthreads();
    }

    // final h(27,27): buf 1, slot 0
    if (tid < BT * HID) {
        int bl = tid >> 6, h = tid & 63;
        Hout[(d * BATCH + tile * BT + bl) * HID + h] = (float)Fh[1][bl][h];
    }
}

__global__ __launch_bounds__(256, 1)
void fc_kernel(const float* __restrict__ Hin,  // [4][B][64]
               const float* __restrict__ W1, const float* __restrict__ b1,
               const float* __restrict__ W2, const float* __restrict__ b2,
               float* __restrict__ out)        // [B][10]
{
    const int b = blockIdx.x;
    const int tid = threadIdx.x;
    __shared__ float hrow[NDIR * HID];
    __shared__ float z1[FC_HD];
    __shared__ float w2s[FC_HD * OUT_N];
    __shared__ float z2[OUT_N];

    hrow[tid] = Hin[(tid >> 6) * BATCH * HID + b * HID + (tid & 63)];
    for (int i = tid; i < FC_HD * OUT_N; i += 256) w2s[i] = W2[i];
    __syncthreads();

    for (int j = tid; j < FC_HD; j += 256) {
        float s = b1[j];
#pragma unroll 8
        for (int f = 0; f < NDIR * HID; ++f) s += hrow[f] * W1[f * FC_HD + j];
        z1[j] = fmaxf(s, 0.0f);
    }
    __syncthreads();

    if (tid < OUT_N) {
        float s = b2[tid];
        for (int i = 0; i < FC_HD; ++i) s += z1[i] * w2s[i * OUT_N + tid];
        z2[tid] = s;
    }
    __syncthreads();

    if (tid == 0) {
        float m = z2[0];
        for (int j = 1; j < OUT_N; ++j) m = fmaxf(m, z2[j]);
        float s = 0.0f, e[OUT_N];
        for (int j = 0; j < OUT_N; ++j) { e[j] = __expf(z2[j] - m); s += e[j]; }
        float inv = 1.0f / s;
        for (int j = 0; j < OUT_N; ++j) out[b * OUT_N + j] = e[j] * inv;
    }
}

extern "C" void kernel_launch(void* const* d_in, const int* in_sizes, int n_in,
                              void* d_out, int out_size, void* d_ws, size_t ws_size,
                              hipStream_t stream) {
    const float* x  = (const float*)d_in[0];
    const float* Wx = (const float*)d_in[1];
    const float* U  = (const float*)d_in[2];
    const float* bs = (const float*)d_in[3];
    const float* W1 = (const float*)d_in[4];
    const float* b1 = (const float*)d_in[5];
    const float* W2 = (const float*)d_in[6];
    const float* b2 = (const float*)d_in[7];
    float* out = (float*)d_out;
    float* Hws = (float*)d_ws;   // [4][128][64] fp32 = 128 KiB

    mdlstm_kernel<<<NDIR * (BATCH / BT), 512, 0, stream>>>(x, Wx, U, bs, Hws);
    fc_kernel<<<BATCH, 256, 0, stream>>>(Hws, W1, b1, W2, b2, out);
}

// Round 4
// 161.738 us; speedup vs baseline: 1.6405x; 1.1267x over previous
//
#include <hip/hip_runtime.h>
#include <hip/hip_bf16.h>

// 2D-MDLSTM (4 directions) + FC head for MI355X — round 4.
//
// R3 post-mortem: mdlstm 103.5 us, but total 182 us. The ~79 us gap is
// constant across rounds => fc_kernel (~70 us: 1 wave/SIMD, 512 serial
// global loads/thread, 512-iter loop on 10 threads). This round:
//  - fc rewritten: WG per batch row; z1 (512 cols) by 256 threads x2 cols
//    with coalesced W1 reads; z2 via 16x16 slice-parallel partials + LDS
//    tree; softmax over 10 trivial. Expect ~6-10 us.
//  - mdlstm: branchless epilogue (clamped dup rows compute identical
//    values => unconditional dup writes are benign). Otherwise unchanged
//    (103 us known-good).

#define GRIDN 28
#define BATCH 128
#define HID   64
#define NDIR  4
#define FC_HD 512
#define OUT_N 10
#define BT    2
#define NSLOT 29          // 28 frontier rows + permanent-zero row (r = -1)
#define S_H   104         // f16/slot: [0,64) h | [64]=x [65]=1 [66,96)=0 | 8 pad
#define S_C   68          // float/slot: 64 c + 4 pad

typedef _Float16 f16;
typedef _Float16 f16x8 __attribute__((ext_vector_type(8)));
typedef float    f32x4 __attribute__((ext_vector_type(4)));

__device__ __forceinline__ float sigf(float x) {
    return __builtin_amdgcn_rcpf(1.0f + __expf(-x));
}
__device__ __forceinline__ float tanh_fast(float x) {
    return 1.0f - 2.0f * __builtin_amdgcn_rcpf(1.0f + __expf(2.0f * x));
}

__global__ __launch_bounds__(512)
void mdlstm_kernel(const float* __restrict__ x,    // [B][28][28]
                   const float* __restrict__ Wx,   // [4][320]
                   const float* __restrict__ U,    // [4][128][320]
                   const float* __restrict__ bias, // [4][320]
                   float* __restrict__ Hout)       // [4][B][64]
{
    const int d    = blockIdx.x & 3;
    const int tile = blockIdx.x >> 2;     // 0..63 batch-pair
    const int tid  = threadIdx.x;
    const int lane = tid & 63;
    const int wave = tid >> 6;            // 0..7
    const int wm   = wave >> 2;           // tile parity 0/1
    const int wh   = wave & 3;            // h-subtile (n = wh*16 + l16)
    const int l16  = lane & 15;
    const int q    = lane >> 4;
    const int nb   = wh * 16 + l16;       // this lane's h index 0..63

    __shared__ __align__(16) f16 Fh[2][BT][NSLOT * S_H];
    __shared__ float             Fc[2][BT][NSLOT * S_C];
    __shared__ float             xs[GRIDN][GRIDN][BT];

    for (int i = tid; i < 2 * BT * NSLOT * S_H; i += 512) ((f16*)Fh)[i] = (f16)0.0f;
    for (int i = tid; i < 2 * BT * NSLOT * S_C; i += 512) ((float*)Fc)[i] = 0.0f;
    for (int i = tid; i < GRIDN * GRIDN * BT; i += 512) {
        int bl = i & 1, rc = i >> 1, c = rc % GRIDN, r = rc / GRIDN;
        int rr = (d & 2) ? (GRIDN - 1 - r) : r;
        int cc = (d & 1) ? (GRIDN - 1 - c) : c;
        xs[r][c][bl] = x[((tile * BT + bl) * GRIDN + rr) * GRIDN + cc];
    }

    // ---- B-fragments in registers: 5 gates x 5 ks = 25 x f16x8 (100 VGPR)
    // ks 0..3: U[k = ks*32 + q*8 + j][n];  ks 4: {Wx[n], bias[n], 0,...} @ q==0
    f16x8 bf[5][5];
#pragma unroll
    for (int g = 0; g < 5; ++g) {
        int n = g * 64 + nb;
#pragma unroll
        for (int ks = 0; ks < 4; ++ks) {
            f16x8 v;
            int kb = ks * 32 + q * 8;
#pragma unroll
            for (int j = 0; j < 8; ++j)
                v[j] = (f16)U[(d * 128 + kb + j) * 320 + n];
            bf[g][ks] = v;
        }
        f16x8 v5 = {(f16)0, (f16)0, (f16)0, (f16)0, (f16)0, (f16)0, (f16)0, (f16)0};
        if (q == 0) {
            v5[0] = (f16)Wx[d * 320 + n];
            v5[1] = (f16)bias[d * 320 + n];
        }
        bf[g][4] = v5;
    }
    __syncthreads();   // zero-init complete

    // ones in the x-region ([65]=1) of every slot, both buffers; seed x(0,0)
    if (tid < 2 * BT * NSLOT) {
        int buf = tid / (BT * NSLOT), rem = tid % (BT * NSLOT);
        int b = rem / NSLOT, sl = rem % NSLOT;
        Fh[buf][b][sl * S_H + 65] = (f16)1.0f;
    }
    if (tid < BT) Fh[0][tid][27 * S_H + 64] = (f16)xs[0][0][tid];
    __syncthreads();

    for (int t = 0; t < 2 * GRIDN - 1; ++t) {
        const int rlo = (t > GRIDN - 1) ? (t - (GRIDN - 1)) : 0;
        const int rhi = (t < GRIDN - 1) ? t : (GRIDN - 1);
        const int k   = rhi - rlo + 1;
        const int nM  = (2 * k + 15) >> 4;
        const int br  = t & 1, bw = br ^ 1;

        // stage x for diagonal t+1 into the write buffer (wave 7, often idle)
        if (t < 2 * GRIDN - 2 && tid >= 456) {
            int idx = tid - 456, b = idx & 1, j = idx >> 1;
            int rlo2 = (t + 1 > GRIDN - 1) ? (t + 1 - (GRIDN - 1)) : 0;
            int rhi2 = (t + 1 < GRIDN - 1) ? (t + 1) : (GRIDN - 1);
            if (j <= rhi2 - rlo2) {
                int r = rlo2 + j;
                Fh[bw][b][(27 - r) * S_H + 64] = (f16)xs[r][t + 1 - r][b];
            }
        }

        for (int mt = wm; mt < nM; mt += 2) {
            // ---- A fragments: task row mA -> (batch bA, grid row rA)
            int mA = mt * 16 + l16;
            int jA = mA >> 1; if (jA > k - 1) jA = k - 1;
            int bA = mA & 1;
            int slA = 27 - (rlo + jA);
            const f16* ab = &Fh[br][bA][slA * S_H];
            f16x8 a0 = *(const f16x8*)(ab + q * 8);              // h_left k 0..63
            f16x8 a1 = *(const f16x8*)(ab + 32 + q * 8);
            f16x8 a2 = *(const f16x8*)(ab + S_H + q * 8);        // h_up   k 64..127
            f16x8 a3 = *(const f16x8*)(ab + S_H + 32 + q * 8);
            f16x8 a4 = *(const f16x8*)(ab + 64 + q * 8);         // {x,1,0..} k 128..159

            f32x4 acc[5];
#pragma unroll
            for (int g = 0; g < 5; ++g) acc[g] = (f32x4){0.f, 0.f, 0.f, 0.f};
#pragma unroll
            for (int g = 0; g < 5; ++g) acc[g] = __builtin_amdgcn_mfma_f32_16x16x32_f16(a0, bf[g][0], acc[g], 0, 0, 0);
#pragma unroll
            for (int g = 0; g < 5; ++g) acc[g] = __builtin_amdgcn_mfma_f32_16x16x32_f16(a1, bf[g][1], acc[g], 0, 0, 0);
#pragma unroll
            for (int g = 0; g < 5; ++g) acc[g] = __builtin_amdgcn_mfma_f32_16x16x32_f16(a2, bf[g][2], acc[g], 0, 0, 0);
#pragma unroll
            for (int g = 0; g < 5; ++g) acc[g] = __builtin_amdgcn_mfma_f32_16x16x32_f16(a3, bf[g][3], acc[g], 0, 0, 0);
#pragma unroll
            for (int g = 0; g < 5; ++g) acc[g] = __builtin_amdgcn_mfma_f32_16x16x32_f16(a4, bf[g][4], acc[g], 0, 0, 0);

            // ---- gates + state, BRANCHLESS.  D row rd = mt*16 + q*4 + i:
            //   i=0: (b0, j0)  i=1: (b1, j0)  i=2: (b0, j0+1)  i=3: (b1, j0+1)
            // Padding rows are clamped (jj = k-1); their A-row was clamped the
            // same way, so acc/cl/cu and hence (cn,hn) are IDENTICAL to the
            // clamp target's -> unconditional duplicate writes are benign
            // (same instruction, same address, same value; never cross-wave).
            int j0  = mt * 8 + q * 2;
            int jj0 = (j0     > k - 1) ? k - 1 : j0;
            int jj1 = (j0 + 1 > k - 1) ? k - 1 : j0 + 1;
            int sl0 = 27 - (rlo + jj0);
            int sl1 = 27 - (rlo + jj1);
#pragma unroll
            for (int i = 0; i < 4; ++i) {
                int  b  = i & 1;
                int  sl = (i < 2) ? sl0 : sl1;
                float cl = Fc[br][b][sl * S_C + nb];
                float cu = Fc[br][b][(sl + 1) * S_C + nb];
                float ig = sigf(acc[0][i]);
                float f1 = sigf(acc[1][i]);
                float f2 = sigf(acc[2][i]);
                float og = sigf(acc[3][i]);
                float gg = tanh_fast(acc[4][i]);
                float cn = ig * gg + f1 * cl + f2 * cu;
                float hn = og * tanh_fast(cn);
                Fc[bw][b][sl * S_C + nb] = cn;
                Fh[bw][b][sl * S_H + nb] = (f16)hn;
            }
        }
        __syncthreads();
    }

    // final h(27,27): buf 1, slot 0
    if (tid < BT * HID) {
        int bl = tid >> 6, h = tid & 63;
        Hout[(d * BATCH + tile * BT + bl) * HID + h] = (float)Fh[1][bl][h];
    }
}

// FC head, one WG per batch row. z1 (512 cols) by 256 threads x 2 cols with
// coalesced W1 reads; z2 via 16-slice x 16-col partials + LDS reduce;
// softmax over 10 by one thread.
__global__ __launch_bounds__(256)
void fc_kernel(const float* __restrict__ Hin,  // [4][B][64]
               const float* __restrict__ W1, const float* __restrict__ b1,
               const float* __restrict__ W2, const float* __restrict__ b2,
               float* __restrict__ out)        // [B][10]
{
    const int b   = blockIdx.x;
    const int tid = threadIdx.x;
    __shared__ float hrow[NDIR * HID];
    __shared__ float z1[FC_HD];
    __shared__ float ps[16][16];
    __shared__ float z2[16];

    hrow[tid] = Hin[(tid >> 6) * (BATCH * HID) + b * HID + (tid & 63)];
    __syncthreads();

    // ---- z1 = relu(hrow @ W1 + b1): each thread cols {tid, tid+256}
    {
        float s0 = b1[tid], s1 = b1[tid + 256];
#pragma unroll 8
        for (int f = 0; f < NDIR * HID; ++f) {
            float h = hrow[f];
            s0 += h * W1[f * FC_HD + tid];
            s1 += h * W1[f * FC_HD + tid + 256];
        }
        z1[tid]       = fmaxf(s0, 0.0f);
        z1[tid + 256] = fmaxf(s1, 0.0f);
    }
    __syncthreads();

    // ---- z2 partials: j = tid&15 (10 used), slice = tid>>4 covers 32 k each
    {
        int j = tid & 15, sl = tid >> 4;
        float s = 0.0f;
        if (j < OUT_N) {
#pragma unroll
            for (int i = 0; i < 32; ++i) {
                int kk = sl * 32 + i;
                s += z1[kk] * W2[kk * OUT_N + j];
            }
        }
        ps[sl][j] = s;
    }
    __syncthreads();

    if (tid < OUT_N) {
        float s = b2[tid];
#pragma unroll
        for (int sl = 0; sl < 16; ++sl) s += ps[sl][tid];
        z2[tid] = s;
    }
    __syncthreads();

    if (tid == 0) {
        float m = z2[0];
        for (int j = 1; j < OUT_N; ++j) m = fmaxf(m, z2[j]);
        float sum = 0.0f, e[OUT_N];
        for (int j = 0; j < OUT_N; ++j) { e[j] = __expf(z2[j] - m); sum += e[j]; }
        float inv = 1.0f / sum;
        for (int j = 0; j < OUT_N; ++j) out[b * OUT_N + j] = e[j] * inv;
    }
}

extern "C" void kernel_launch(void* const* d_in, const int* in_sizes, int n_in,
                              void* d_out, int out_size, void* d_ws, size_t ws_size,
                              hipStream_t stream) {
    const float* x  = (const float*)d_in[0];
    const float* Wx = (const float*)d_in[1];
    const float* U  = (const float*)d_in[2];
    const float* bs = (const float*)d_in[3];
    const float* W1 = (const float*)d_in[4];
    const float* b1 = (const float*)d_in[5];
    const float* W2 = (const float*)d_in[6];
    const float* b2 = (const float*)d_in[7];
    float* out = (float*)d_out;
    float* Hws = (float*)d_ws;   // [4][128][64] fp32 = 128 KiB

    mdlstm_kernel<<<NDIR * (BATCH / BT), 512, 0, stream>>>(x, Wx, U, bs, Hws);
    fc_kernel<<<BATCH, 256, 0, stream>>>(Hws, W1, b1, W2, b2, out);
}